// Round 1
// baseline (80.577 us; speedup 1.0000x reference)
//
#include <hip/hip_runtime.h>

// InvButterflyLayer: B=256, MID=16384, OUT=16384, C=16, NLVL=8, MIDF=64, NB=256
// Only t < 2^(8-lvl) of each level feeds the final output (reference slices t=0
// at the end), so we compute just that prefix: level0 needs t<256 -> x[0:8224).
//
// Phase 1: per-b block (256 blocks, 256 threads). Levels 0..5 in LDS ping-pong.
//          Each thread computes BOTH complex halves (i=0,1) of one (n,t) vector
//          so staged weights are reused 2x. Writes S5[n5][t][bi][c] to d_ws.
// Phase 2: block = (n6, 64-wide bi-chunk) (64x8 blocks, 256 threads).
//          Levels 6..8 + 16->64 dense + complex recombination.
//
// Outputs: out[0 .. 2097152)           = (R[:,:,0]-I[:,:,1])/MID   (B x 8192)
//          out[2097152 .. 4194304)     = R[:,:,1]                  (B x 8192)

#define OUT_HALF 2097152

__global__ __launch_bounds__(256, 1)
void ibf_phase1(const float* __restrict__ in_data,
                const float* __restrict__ mid_dense,
                const float* __restrict__ in_filter,
                const float* __restrict__ in_bias,
                const float* __restrict__ filters,
                const float* __restrict__ biases,
                float* __restrict__ S5) {
    // LDS layout (floats):
    //  F    [0,1024)        in_filter 64x16
    //  bin  [1024,1040)
    //  bufA [1040,9744)     512 vectors * 17
    //  bufB [9744,18448)    512 vectors * 17
    //  X0   [18448,26929)   8481 (x, i=0, +1 pad per 32) -- dead after level 0
    //  X1   [26929,35410)   8481 (x, i=1)
    //  WL   [18448,34960)   aliases X: 32 nodes * 516    -- used levels 1..5
    //  LB   [34960,35472)   level biases (<= 32*16)
    __shared__ float sm[35472];
    float* F    = sm;
    float* bin  = sm + 1024;
    float* bufA = sm + 1040;
    float* bufB = sm + 9744;
    float* X0   = sm + 18448;
    float* X1   = sm + 26929;
    float* WL   = sm + 18448;
    float* LB   = sm + 34960;

    const int tid = threadIdx.x;
    const int b   = blockIdx.x;

    // stage in_filter (1024 floats) + in_bias
    {
        const float4* src = (const float4*)in_filter;
        if (tid < 256) ((float4*)F)[tid] = src[tid];
        if (tid < 16)  bin[tid] = in_bias[tid];
    }
    // stage x = in_data[b,m,:] * mid_dense[0,m,:], m in [0,8224), pad every 32
    {
        const float* row = in_data + (size_t)b * (16384 * 2);
        for (int m = tid; m < 8224; m += 256) {
            float2 v  = *(const float2*)(row + 2 * m);
            float2 md = *(const float2*)(mid_dense + 2 * m);
            int mp = m + (m >> 5);
            X0[mp] = v.x * md.x;
            X1[mp] = v.y * md.y;
        }
    }
    __syncthreads();

    // level 0: s[i][t][c] = relu(bias + sum_{w<64} x_i[32t+w] * F[w][c]), t=tid
    {
        const int t = tid;
        float acc0[16], acc1[16];
#pragma unroll
        for (int c = 0; c < 16; c++) { float bv = bin[c]; acc0[c] = bv; acc1[c] = bv; }
        const int base = 33 * t;
        for (int w = 0; w < 64; w++) {
            const int xa = base + w + (w >> 5);
            float p0 = X0[xa];
            float p1 = X1[xa];
            const float4* F4 = (const float4*)(F + 16 * w);
#pragma unroll
            for (int q = 0; q < 4; q++) {
                float4 fv = F4[q];
                acc0[4*q+0] += p0 * fv.x; acc0[4*q+1] += p0 * fv.y;
                acc0[4*q+2] += p0 * fv.z; acc0[4*q+3] += p0 * fv.w;
                acc1[4*q+0] += p1 * fv.x; acc1[4*q+1] += p1 * fv.y;
                acc1[4*q+2] += p1 * fv.z; acc1[4*q+3] += p1 * fv.w;
            }
        }
        float* d0 = bufA + t * 17;            // vec = i*256 + t
        float* d1 = bufA + (256 + t) * 17;
#pragma unroll
        for (int c = 0; c < 16; c++) {
            d0[c] = fmaxf(acc0[c], 0.0f);
            d1[c] = fmaxf(acc1[c], 0.0f);
        }
    }
    __syncthreads();

    // levels 1..5: state[n][t][d] = relu(b[n][d] + sum_{k,c} P[n>>1][2t+k][c] * W[n][k][c][d])
    float* P = bufA;
    float* N = bufB;
    for (int lvl = 1; lvl <= 5; lvl++) {
        const int nb = 1 << lvl;
        const int sh = 8 - lvl;
        const int T  = 1 << sh;
        const int Tp = T << 1;
        // stage this level's weights (nb*512 floats, node stride 516) + biases
        {
            const float4* Wg = (const float4*)(filters + (size_t)(lvl - 1) * (256 * 512));
            const int n4 = nb * 128;
            for (int i4 = tid; i4 < n4; i4 += 256) {
                int n = i4 >> 7, q4 = i4 & 127;
                ((float4*)(WL + n * 516))[q4] = Wg[i4];
            }
            const float* Bg = biases + (size_t)(lvl - 1) * (256 * 16);
            for (int i = tid; i < nb * 16; i += 256) LB[i] = Bg[i];
        }
        __syncthreads();
        {
            const int n = tid >> sh;
            const int t = tid & (T - 1);
            float acc0[16], acc1[16];
            const float* lb = LB + n * 16;
#pragma unroll
            for (int d = 0; d < 16; d++) { float bv = lb[d]; acc0[d] = bv; acc1[d] = bv; }
            const int vp0 = (n >> 1) * Tp + 2 * t;   // i=1 parent: +256
            const float* Wn = WL + n * 516;
#pragma unroll
            for (int k = 0; k < 2; k++) {
                const float* p0v = P + (vp0 + k) * 17;
                const float* p1v = P + (vp0 + k + 256) * 17;
#pragma unroll
                for (int c = 0; c < 16; c++) {
                    float p0 = p0v[c];
                    float p1 = p1v[c];
                    const float4* w4 = (const float4*)(Wn + (k * 16 + c) * 16);
#pragma unroll
                    for (int q = 0; q < 4; q++) {
                        float4 wv = w4[q];
                        acc0[4*q+0] += p0 * wv.x; acc0[4*q+1] += p0 * wv.y;
                        acc0[4*q+2] += p0 * wv.z; acc0[4*q+3] += p0 * wv.w;
                        acc1[4*q+0] += p1 * wv.x; acc1[4*q+1] += p1 * wv.y;
                        acc1[4*q+2] += p1 * wv.z; acc1[4*q+3] += p1 * wv.w;
                    }
                }
            }
            const int vn = n * T + t;                 // == tid
            float* d0 = N + vn * 17;
            float* d1 = N + (vn + 256) * 17;
#pragma unroll
            for (int d = 0; d < 16; d++) {
                d0[d] = fmaxf(acc0[d], 0.0f);
                d1[d] = fmaxf(acc1[d], 0.0f);
            }
        }
        __syncthreads();
        float* tmp = P; P = N; N = tmp;
    }

    // write S5: P vec = i*256 + n5*8 + t  ->  S5[n5][t][bi=2b+i][c]
    for (int v = tid; v < 512; v += 256) {
        const int i  = v >> 8;
        const int r  = v & 255;
        const int n5 = r >> 3;
        const int t  = r & 7;
        const float* src = P + v * 17;
        float* dst = S5 + (((size_t)n5 * 8 + t) * 512 + (2 * b + i)) * 16;
#pragma unroll
        for (int q = 0; q < 4; q++) {
            ((float4*)dst)[q] = make_float4(src[4*q], src[4*q+1], src[4*q+2], src[4*q+3]);
        }
    }
}

__global__ __launch_bounds__(256, 1)
void ibf_phase2(const float* __restrict__ filters,
                const float* __restrict__ biases,
                const float* __restrict__ fea_dense,
                const float* __restrict__ S5,
                float* __restrict__ out) {
    // LDS layout (floats): weight reads are wave-uniform -> no padding needed.
    //  W6 [0,512)  W7 [512,1536)  W8 [1536,3584)  BB [3584,3696)
    //  FE [3696,7792)  S [7792,16496)  V6 [16496,20848)  V7 [20848,25200)  V8 [25200,29552)
    __shared__ float sm[29552];
    float* W6 = sm;
    float* W7 = sm + 512;
    float* W8 = sm + 1536;
    float* BB = sm + 3584;
    float* FE = sm + 3696;
    float* S  = sm + 7792;
    float* V6 = sm + 16496;
    float* V7 = sm + 20848;
    float* V8 = sm + 25200;

    const int tid   = threadIdx.x;
    const int n6    = blockIdx.x;     // 0..63
    const int chunk = blockIdx.y;     // 0..7
    const int bi0   = chunk << 6;

    // stage weights / biases / fea / S-chunk
    {
        const float4* w6g = (const float4*)(filters + (size_t)(5 * 256 + n6) * 512);
        if (tid < 128) ((float4*)W6)[tid] = w6g[tid];
        const float4* w7g = (const float4*)(filters + (size_t)(6 * 256 + 2 * n6) * 512);
        if (tid < 256) ((float4*)W7)[tid] = w7g[tid];
        const float4* w8g = (const float4*)(filters + (size_t)(7 * 256 + 4 * n6) * 512);
        for (int i4 = tid; i4 < 512; i4 += 256) ((float4*)W8)[i4] = w8g[i4];
        if (tid < 16) BB[tid]      = biases[(size_t)(5 * 256 + n6)     * 16 + tid];
        if (tid < 32) BB[16 + tid] = biases[(size_t)(6 * 256 + 2 * n6) * 16 + tid];
        if (tid < 64) BB[48 + tid] = biases[(size_t)(7 * 256 + 4 * n6) * 16 + tid];
        const float4* feg = (const float4*)(fea_dense + (size_t)(4 * n6) * 1024);
        for (int i4 = tid; i4 < 1024; i4 += 256) ((float4*)FE)[i4] = feg[i4];
        // S5[n5][t][bi0+bi][c] -> S[(t*64+bi)*17 + c]
        const int n5 = n6 >> 1;
        const float* sg = S5 + ((size_t)n5 * 8 * 512 + bi0) * 16;
        for (int i4 = tid; i4 < 2048; i4 += 256) {
            int t = i4 >> 8, r4 = i4 & 255;
            float4 v = ((const float4*)(sg + (size_t)t * 8192))[r4];
            int bi = r4 >> 2, c4 = (r4 & 3) * 4;
            float* d = S + (t * 64 + bi) * 17 + c4;
            d[0] = v.x; d[1] = v.y; d[2] = v.z; d[3] = v.w;
        }
    }
    __syncthreads();

    // level 6: thread (t=tid>>6, bi=tid&63)
    {
        const int t = tid >> 6, bi = tid & 63;
        float acc[16];
#pragma unroll
        for (int d = 0; d < 16; d++) acc[d] = BB[d];
#pragma unroll
        for (int k = 0; k < 2; k++) {
            const float* pv = S + ((2 * t + k) * 64 + bi) * 17;
#pragma unroll
            for (int c = 0; c < 16; c++) {
                float p = pv[c];
                const float4* w4 = (const float4*)(W6 + (k * 16 + c) * 16);
#pragma unroll
                for (int q = 0; q < 4; q++) {
                    float4 wv = w4[q];
                    acc[4*q+0] += p * wv.x; acc[4*q+1] += p * wv.y;
                    acc[4*q+2] += p * wv.z; acc[4*q+3] += p * wv.w;
                }
            }
        }
        float* dst = V6 + (t * 64 + bi) * 17;
#pragma unroll
        for (int d = 0; d < 16; d++) dst[d] = fmaxf(acc[d], 0.0f);
    }
    __syncthreads();

    // level 7: thread (j=tid>>7, t=(tid>>6)&1, bi=tid&63); node 2*n6+j
    {
        const int j = tid >> 7, t = (tid >> 6) & 1, bi = tid & 63;
        float acc[16];
#pragma unroll
        for (int d = 0; d < 16; d++) acc[d] = BB[16 + j * 16 + d];
        const float* Wn = W7 + j * 512;
#pragma unroll
        for (int k = 0; k < 2; k++) {
            const float* pv = V6 + ((2 * t + k) * 64 + bi) * 17;
#pragma unroll
            for (int c = 0; c < 16; c++) {
                float p = pv[c];
                const float4* w4 = (const float4*)(Wn + (k * 16 + c) * 16);
#pragma unroll
                for (int q = 0; q < 4; q++) {
                    float4 wv = w4[q];
                    acc[4*q+0] += p * wv.x; acc[4*q+1] += p * wv.y;
                    acc[4*q+2] += p * wv.z; acc[4*q+3] += p * wv.w;
                }
            }
        }
        float* dst = V7 + ((j * 2 + t) * 64 + bi) * 17;
#pragma unroll
        for (int d = 0; d < 16; d++) dst[d] = fmaxf(acc[d], 0.0f);
    }
    __syncthreads();

    // level 8: thread (j=tid>>6, bi=tid&63); node 4*n6+j, t=0
    {
        const int j = tid >> 6, bi = tid & 63;
        float acc[16];
#pragma unroll
        for (int d = 0; d < 16; d++) acc[d] = BB[48 + j * 16 + d];
        const float* Wn = W8 + j * 512;
#pragma unroll
        for (int k = 0; k < 2; k++) {
            const float* pv = V7 + (((j >> 1) * 2 + k) * 64 + bi) * 17;
#pragma unroll
            for (int c = 0; c < 16; c++) {
                float p = pv[c];
                const float4* w4 = (const float4*)(Wn + (k * 16 + c) * 16);
#pragma unroll
                for (int q = 0; q < 4; q++) {
                    float4 wv = w4[q];
                    acc[4*q+0] += p * wv.x; acc[4*q+1] += p * wv.y;
                    acc[4*q+2] += p * wv.z; acc[4*q+3] += p * wv.w;
                }
            }
        }
        float* dst = V8 + (j * 64 + bi) * 17;
#pragma unroll
        for (int d = 0; d < 16; d++) dst[d] = fmaxf(acc[d], 0.0f);
    }
    __syncthreads();

    // dense 16->64 + complex recombination
    // thread (j=tid>>6, bl=(tid>>1)&31, half=tid&1); n8=4*n6+j; b=chunk*32+bl
    {
        const int j    = tid >> 6;
        const int bl   = (tid >> 1) & 31;
        const int half = tid & 1;
        const int n8   = 4 * n6 + j;
        const int bglob = (chunk << 5) + bl;
        float ve[16], vo[16];
        const float* pe = V8 + (j * 64 + 2 * bl) * 17;   // i=0 (bi even)
        const float* po = pe + 17;                        // i=1
#pragma unroll
        for (int c = 0; c < 16; c++) { ve[c] = pe[c]; vo[c] = po[c]; }
        const float* fj = FE + j * 1024;
        float o0[16], o1[16];
#pragma unroll
        for (int uu = 0; uu < 16; uu++) {
            const int u = half * 16 + uu;
            float r0 = 0.0f, r1 = 0.0f, i1 = 0.0f;
#pragma unroll
            for (int c = 0; c < 16; c++) {
                float2 fe = *(const float2*)(fj + c * 64 + 2 * u);
                r0 += ve[c] * fe.x;
                r1 += ve[c] * fe.y;
                i1 += vo[c] * fe.y;
            }
            o0[uu] = (r0 - i1) * (1.0f / 16384.0f);
            o1[uu] = r1;
        }
        float* o0p = out + (size_t)bglob * 8192 + n8 * 32 + half * 16;
        float* o1p = o0p + OUT_HALF;
#pragma unroll
        for (int q = 0; q < 4; q++) {
            ((float4*)o0p)[q] = make_float4(o0[4*q], o0[4*q+1], o0[4*q+2], o0[4*q+3]);
            ((float4*)o1p)[q] = make_float4(o1[4*q], o1[4*q+1], o1[4*q+2], o1[4*q+3]);
        }
    }
}

extern "C" void kernel_launch(void* const* d_in, const int* in_sizes, int n_in,
                              void* d_out, int out_size, void* d_ws, size_t ws_size,
                              hipStream_t stream) {
    const float* in_data   = (const float*)d_in[0];
    const float* mid_dense = (const float*)d_in[1];
    const float* in_filter = (const float*)d_in[2];
    const float* in_bias   = (const float*)d_in[3];
    const float* filters   = (const float*)d_in[4];
    const float* biases    = (const float*)d_in[5];
    const float* fea_dense = (const float*)d_in[6];
    float* out = (float*)d_out;
    float* S5  = (float*)d_ws;   // 32*8*512*16 floats = 8 MB

    ibf_phase1<<<256, 256, 0, stream>>>(in_data, mid_dense, in_filter, in_bias,
                                        filters, biases, S5);
    ibf_phase2<<<dim3(64, 8), 256, 0, stream>>>(filters, biases, fea_dense, S5, out);
}